// Round 4
// baseline (49.959 us; speedup 1.0000x reference)
//
#include <hip/hip_runtime.h>

typedef unsigned short ushort4v __attribute__((ext_vector_type(4)));

namespace {
constexpr int kB = 2, kC = 256, kH = 100, kW = 152;
constexpr int kN = 1000;
constexpr int kPH = 7, kPW = 7, kSR = 2;
constexpr float kScale = 0.0625f;
constexpr int kHW = kH * kW;                 // 15200
constexpr int kBins = kPH * kPW;             // 49
constexpr int kOutPerRoi = kC * kBins;       // 12544
constexpr int kStrideE = 258;                // bf16 elems
constexpr int kNY = kPH * kSR;               // 14
constexpr int kNX = kPW * kSR;               // 14
constexpr int kThreads = 512;
constexpr int kNXcd = 8;
constexpr int kPerXcd = (kN + kNXcd - 1) / kNXcd;  // 125
}

__device__ __forceinline__ float b2f(unsigned short u) {
  union { unsigned int i; float f; } x; x.i = ((unsigned int)u) << 16; return x.f;
}
__device__ __forceinline__ unsigned short f2b(float f) {
  union { float f; unsigned int i; } x; x.f = f;
  return (unsigned short)((x.i + 0x7FFFu + ((x.i >> 16) & 1u)) >> 16);  // RNE
}

// bucket ROIs by (batch, y-octile) so each XCD's blocks share an L2-sized band
__global__ __launch_bounds__(1024) void bucket_k(const float* __restrict__ rois,
                                                 int* __restrict__ perm) {
  __shared__ int cnt[16];
  __shared__ int pfx[16];
  const int t = threadIdx.x;
  if (t < 16) cnt[t] = 0;
  __syncthreads();
  int b = 0, rank = 0;
  if (t < kN) {
    const int batch = (int)rois[t * 5 + 0];
    const float cy = (rois[t * 5 + 2] + rois[t * 5 + 4]) * 0.5f * kScale;
    int yb = (int)(cy * (8.0f / (float)kH));
    yb = yb < 0 ? 0 : (yb > 7 ? 7 : yb);
    b = batch * 8 + yb;
    rank = atomicAdd(&cnt[b], 1);
  }
  __syncthreads();
  if (t == 0) {
    int run = 0;
    for (int i = 0; i < 16; ++i) { pfx[i] = run; run += cnt[i]; }
  }
  __syncthreads();
  if (t < kN) perm[pfx[b] + rank] = t;
}

// (B,C,H,W) f32 -> (B,H*W,C) bf16, tiled 32x32 transpose
__global__ __launch_bounds__(256) void transpose_k(const float* __restrict__ in,
                                                   unsigned short* __restrict__ out) {
  __shared__ float tile[32][33];
  const int b = blockIdx.z;
  const int hw0 = blockIdx.x * 32;
  const int c0 = blockIdx.y * 32;
  const int tx = threadIdx.x;   // 0..7  (x4 floats)
  const int ty = threadIdx.y;   // 0..31
  const float4 v = *(const float4*)(in + (size_t)b * kC * kHW +
                                    (size_t)(c0 + ty) * kHW + hw0 + tx * 4);
  tile[tx * 4 + 0][ty] = v.x;
  tile[tx * 4 + 1][ty] = v.y;
  tile[tx * 4 + 2][ty] = v.z;
  tile[tx * 4 + 3][ty] = v.w;
  __syncthreads();
  ushort4v w;
  w.x = f2b(tile[ty][tx * 4 + 0]);
  w.y = f2b(tile[ty][tx * 4 + 1]);
  w.z = f2b(tile[ty][tx * 4 + 2]);
  w.w = f2b(tile[ty][tx * 4 + 3]);
  *(ushort4v*)(out + (size_t)b * kHW * kC + (size_t)(hw0 + ty) * kC + c0 + tx * 4) = w;
}

// one block per ROI (via XCD-banded permutation); 8 waves; lane*4 covers C
__global__ __launch_bounds__(kThreads, 8) void roialign_k(
    const unsigned short* __restrict__ ft, const float* __restrict__ rois,
    const int* __restrict__ perm, float* __restrict__ out) {
  __shared__ unsigned short sOut[kBins * kStrideE];  // ~24.7 KB
  __shared__ int sYlo[kNY], sXlo[kNX];
  __shared__ float sHy[kNY], sLy[kNY], sHx[kNX], sLx[kNX];
  __shared__ int sB, sN;

  const int t = threadIdx.x;
  if (t == 0) {
    // XCD k (= blockIdx%8) gets sorted positions [k*125, (k+1)*125)
    const int p = (blockIdx.x & 7) * kPerXcd + (blockIdx.x >> 3);
    const int n = perm[p];
    sN = n;
    sB = (int)rois[n * 5 + 0];
  }
  __syncthreads();
  const int n = sN;

  if (t < kNY + kNX) {
    const bool isX = t >= kNY;
    const int i = isX ? t - kNY : t;
    const float x1 = rois[n * 5 + 1] * kScale;
    const float y1 = rois[n * 5 + 2] * kScale;
    const float x2 = rois[n * 5 + 3] * kScale;
    const float y2 = rois[n * 5 + 4] * kScale;
    const float roiw = fmaxf(x2 - x1, 1.0f);
    const float roih = fmaxf(y2 - y1, 1.0f);
    const float start = isX ? x1 : y1;
    const float binsz = isX ? (roiw / kPW) : (roih / kPH);
    const float size = isX ? (float)kW : (float)kH;
    const int p = i / kSR, s = i % kSR;
    const float c = start + p * binsz + (s + 0.5f) * binsz / kSR;
    const bool valid = (c > -1.0f) && (c < size);
    const float cc = fminf(fmaxf(c, 0.0f), size - 1.0f);
    const float lo = fminf(floorf(cc), size - 2.0f);
    const float fr = cc - lo;
    const float wHi = valid ? (1.0f - fr) : 0.0f;
    const float wLo = valid ? fr : 0.0f;
    if (isX) { sXlo[i] = (int)lo; sHx[i] = wHi; sLx[i] = wLo; }
    else     { sYlo[i] = (int)lo; sHy[i] = wHi; sLy[i] = wLo; }
  }
  __syncthreads();

  const int wave = t >> 6;       // 0..7
  const int lane = t & 63;
  const unsigned short* fb = ft + (size_t)sB * kHW * kC + lane * 4;

  for (int bin = wave; bin < kBins; bin += 8) {
    const int ph = bin / kPW, pw = bin % kPW;
    float4 acc = make_float4(0.f, 0.f, 0.f, 0.f);
#pragma unroll
    for (int sy = 0; sy < kSR; ++sy) {
      const int iy = ph * kSR + sy;
      const int ylo = sYlo[iy];
      const float hy = sHy[iy], ly = sLy[iy];
#pragma unroll
      for (int sx = 0; sx < kSR; ++sx) {
        const int ix = pw * kSR + sx;
        const int xlo = sXlo[ix];
        const float hx = sHx[ix], lx = sLx[ix];
        const float w00 = hy * hx, w01 = hy * lx, w10 = ly * hx, w11 = ly * lx;
        const unsigned short* p00 = fb + ((size_t)ylo * kW + xlo) * kC;
        const ushort4v v00 = *(const ushort4v*)(p00);
        const ushort4v v01 = *(const ushort4v*)(p00 + kC);
        const ushort4v v10 = *(const ushort4v*)(p00 + kW * kC);
        const ushort4v v11 = *(const ushort4v*)(p00 + kW * kC + kC);
        acc.x += w00 * b2f(v00.x) + w01 * b2f(v01.x) + w10 * b2f(v10.x) + w11 * b2f(v11.x);
        acc.y += w00 * b2f(v00.y) + w01 * b2f(v01.y) + w10 * b2f(v10.y) + w11 * b2f(v11.y);
        acc.z += w00 * b2f(v00.z) + w01 * b2f(v01.z) + w10 * b2f(v10.z) + w11 * b2f(v11.z);
        acc.w += w00 * b2f(v00.w) + w01 * b2f(v01.w) + w10 * b2f(v10.w) + w11 * b2f(v11.w);
      }
    }
    const int wIdx = bin * (kStrideE / 2) + lane * 2;  // u32 word index
    unsigned int* s32 = (unsigned int*)sOut;
    s32[wIdx + 0] = (unsigned int)f2b(acc.x * 0.25f) |
                    ((unsigned int)f2b(acc.y * 0.25f) << 16);
    s32[wIdx + 1] = (unsigned int)f2b(acc.z * 0.25f) |
                    ((unsigned int)f2b(acc.w * 0.25f) << 16);
  }
  __syncthreads();

  // coalesced float4 write of this ROI's (C,PH,PW) block
  float4* ob4 = (float4*)(out + (size_t)n * kOutPerRoi);
  for (int q = t; q < kOutPerRoi / 4; q += kThreads) {
    const int f = q * 4;
    const int c0 = (f + 0) / kBins, b0 = (f + 0) - c0 * kBins;
    const int c1 = (f + 1) / kBins, b1 = (f + 1) - c1 * kBins;
    const int c2 = (f + 2) / kBins, b2 = (f + 2) - c2 * kBins;
    const int c3 = (f + 3) / kBins, b3 = (f + 3) - c3 * kBins;
    float4 v;
    v.x = b2f(sOut[b0 * kStrideE + c0]);
    v.y = b2f(sOut[b1 * kStrideE + c1]);
    v.z = b2f(sOut[b2 * kStrideE + c2]);
    v.w = b2f(sOut[b3 * kStrideE + c3]);
    ob4[q] = v;
  }
}

extern "C" void kernel_launch(void* const* d_in, const int* in_sizes, int n_in,
                              void* d_out, int out_size, void* d_ws, size_t ws_size,
                              hipStream_t stream) {
  const float* feat = (const float*)d_in[0];
  const float* rois = (const float*)d_in[1];
  float* out = (float*)d_out;
  int* perm = (int*)d_ws;                                   // 4 KB slot
  unsigned short* ft = (unsigned short*)((char*)d_ws + 4096);  // 15.6 MB

  hipLaunchKernelGGL(bucket_k, dim3(1), dim3(1024), 0, stream, rois, perm);
  hipLaunchKernelGGL(transpose_k, dim3(kHW / 32, kC / 32, kB), dim3(8, 32), 0,
                     stream, feat, ft);
  hipLaunchKernelGGL(roialign_k, dim3(kN), dim3(kThreads), 0, stream, ft, rois,
                     perm, out);
}

// Round 5
// 44.138 us; speedup vs baseline: 1.1319x; 1.1319x over previous
//
#include <hip/hip_runtime.h>

typedef unsigned short ushort8v __attribute__((ext_vector_type(8)));

namespace {
constexpr int kB = 2, kC = 256, kH = 100, kW = 152;
constexpr int kN = 1000;
constexpr int kPH = 7, kPW = 7, kSR = 2;
constexpr float kScale = 0.0625f;
constexpr int kHW = kH * kW;                 // 15200
constexpr int kBins = kPH * kPW;             // 49
constexpr int kOutPerRoi = kC * kBins;       // 12544
constexpr int kStrideE = 260;                // bf16 elems; 130 u32 words (8B aligned)
constexpr int kNY = kPH * kSR;               // 14
constexpr int kNX = kPW * kSR;               // 14
constexpr int kThreads = 512;
}

__device__ __forceinline__ float b2f(unsigned short u) {
  union { unsigned int i; float f; } x; x.i = ((unsigned int)u) << 16; return x.f;
}
__device__ __forceinline__ unsigned short f2b(float f) {
  union { float f; unsigned int i; } x; x.f = f;
  return (unsigned short)((x.i + 0x7FFFu + ((x.i >> 16) & 1u)) >> 16);  // RNE
}

// (B,C,H,W) f32 -> (B,H*W,C) bf16, tiled 32x32 transpose
__global__ __launch_bounds__(256) void transpose_k(const float* __restrict__ in,
                                                   unsigned short* __restrict__ out) {
  __shared__ float tile[32][33];
  const int b = blockIdx.z;
  const int hw0 = blockIdx.x * 32;
  const int c0 = blockIdx.y * 32;
  const int tx = threadIdx.x;   // 0..7  (x4 floats)
  const int ty = threadIdx.y;   // 0..31
  const float4 v = *(const float4*)(in + (size_t)b * kC * kHW +
                                    (size_t)(c0 + ty) * kHW + hw0 + tx * 4);
  tile[tx * 4 + 0][ty] = v.x;
  tile[tx * 4 + 1][ty] = v.y;
  tile[tx * 4 + 2][ty] = v.z;
  tile[tx * 4 + 3][ty] = v.w;
  __syncthreads();
  unsigned short w0 = f2b(tile[ty][tx * 4 + 0]);
  unsigned short w1 = f2b(tile[ty][tx * 4 + 1]);
  unsigned short w2 = f2b(tile[ty][tx * 4 + 2]);
  unsigned short w3 = f2b(tile[ty][tx * 4 + 3]);
  unsigned int lo = (unsigned int)w0 | ((unsigned int)w1 << 16);
  unsigned int hi = (unsigned int)w2 | ((unsigned int)w3 << 16);
  unsigned int* dst = (unsigned int*)(out + (size_t)b * kHW * kC +
                                      (size_t)(hw0 + ty) * kC + c0 + tx * 4);
  dst[0] = lo;
  dst[1] = hi;
}

// one block per ROI; 8 waves; per bin: lanes 0-31 = x-lo corner, 32-63 = x-hi,
// each lane 8 channels via one 16B load -> 1KB contiguous per wave instruction
__global__ __launch_bounds__(kThreads, 8) void roialign_k(
    const unsigned short* __restrict__ ft, const float* __restrict__ rois,
    float* __restrict__ out) {
  __shared__ unsigned short sOut[kBins * kStrideE];  // ~24.9 KB
  __shared__ int sYlo[kNY], sXlo[kNX];
  __shared__ float sHy[kNY], sLy[kNY], sHx[kNX], sLx[kNX];
  __shared__ int sB;

  const int n = blockIdx.x;
  const int t = threadIdx.x;

  if (t < kNY + kNX) {
    const bool isX = t >= kNY;
    const int i = isX ? t - kNY : t;
    const float x1 = rois[n * 5 + 1] * kScale;
    const float y1 = rois[n * 5 + 2] * kScale;
    const float x2 = rois[n * 5 + 3] * kScale;
    const float y2 = rois[n * 5 + 4] * kScale;
    const float roiw = fmaxf(x2 - x1, 1.0f);
    const float roih = fmaxf(y2 - y1, 1.0f);
    const float start = isX ? x1 : y1;
    const float binsz = isX ? (roiw / kPW) : (roih / kPH);
    const float size = isX ? (float)kW : (float)kH;
    const int p = i / kSR, s = i % kSR;
    const float c = start + p * binsz + (s + 0.5f) * binsz / kSR;
    const bool valid = (c > -1.0f) && (c < size);
    const float cc = fminf(fmaxf(c, 0.0f), size - 1.0f);
    const float lo = fminf(floorf(cc), size - 2.0f);
    const float fr = cc - lo;
    // fold the 1/(SR*SR)=0.25 average into the weights (0.5 per axis)
    const float wHi = valid ? (1.0f - fr) * 0.5f : 0.0f;
    const float wLo = valid ? fr * 0.5f : 0.0f;
    if (isX) { sXlo[i] = (int)lo; sHx[i] = wHi; sLx[i] = wLo; }
    else     { sYlo[i] = (int)lo; sHy[i] = wHi; sLy[i] = wLo; }
  }
  if (t == 0) sB = (int)rois[n * 5 + 0];
  __syncthreads();

  const int wave = t >> 6;       // 0..7
  const int lane = t & 63;
  const int half = lane >> 5;    // 0: x-lo corner, 1: x-hi corner
  const int sub = lane & 31;     // channel octet index
  const unsigned short* fb = ft + (size_t)sB * kHW * kC + sub * 8;
  unsigned int* s32 = (unsigned int*)sOut;

  for (int bin = wave; bin < kBins; bin += 8) {
    const int ph = bin / kPW, pw = bin % kPW;
    float acc[8] = {0.f, 0.f, 0.f, 0.f, 0.f, 0.f, 0.f, 0.f};
#pragma unroll
    for (int sy = 0; sy < kSR; ++sy) {
      const int iy = ph * kSR + sy;
      const int ylo = sYlo[iy];
      const float hy = sHy[iy], ly = sLy[iy];
#pragma unroll
      for (int sx = 0; sx < kSR; ++sx) {
        const int ix = pw * kSR + sx;
        const int xlo = sXlo[ix];
        const float hxs = half ? sLx[ix] : sHx[ix];   // this half's x-weight
        const float wTop = hy * hxs, wBot = ly * hxs;
        const unsigned short* p0 = fb + ((size_t)(ylo * kW + xlo + half)) * kC;
        const ushort8v v0 = *(const ushort8v*)(p0);            // row ylo
        const ushort8v v1 = *(const ushort8v*)(p0 + kW * kC);  // row ylo+1
#pragma unroll
        for (int k = 0; k < 8; ++k)
          acc[k] += wTop * b2f(v0[k]) + wBot * b2f(v1[k]);
      }
    }
    // merge the two corner-halves: butterfly across lane^32
#pragma unroll
    for (int k = 0; k < 8; ++k) acc[k] += __shfl_xor(acc[k], 32);
    // lane stores 2 u32 words (4 channels), picked by half; 8B-aligned
    const int kBase = half * 4;
    const unsigned int wA = (unsigned int)f2b(acc[kBase + 0]) |
                            ((unsigned int)f2b(acc[kBase + 1]) << 16);
    const unsigned int wB = (unsigned int)f2b(acc[kBase + 2]) |
                            ((unsigned int)f2b(acc[kBase + 3]) << 16);
    const int wIdx = bin * (kStrideE / 2) + sub * 4 + half * 2;
    s32[wIdx + 0] = wA;
    s32[wIdx + 1] = wB;
  }
  __syncthreads();

  // coalesced float4 write of this ROI's (C,PH,PW) block
  float4* ob4 = (float4*)(out + (size_t)n * kOutPerRoi);
  for (int q = t; q < kOutPerRoi / 4; q += kThreads) {
    const int f = q * 4;
    const int c0 = (f + 0) / kBins, b0 = (f + 0) - c0 * kBins;
    const int c1 = (f + 1) / kBins, b1 = (f + 1) - c1 * kBins;
    const int c2 = (f + 2) / kBins, b2 = (f + 2) - c2 * kBins;
    const int c3 = (f + 3) / kBins, b3 = (f + 3) - c3 * kBins;
    float4 v;
    v.x = b2f(sOut[b0 * kStrideE + c0]);
    v.y = b2f(sOut[b1 * kStrideE + c1]);
    v.z = b2f(sOut[b2 * kStrideE + c2]);
    v.w = b2f(sOut[b3 * kStrideE + c3]);
    ob4[q] = v;
  }
}

extern "C" void kernel_launch(void* const* d_in, const int* in_sizes, int n_in,
                              void* d_out, int out_size, void* d_ws, size_t ws_size,
                              hipStream_t stream) {
  const float* feat = (const float*)d_in[0];
  const float* rois = (const float*)d_in[1];
  float* out = (float*)d_out;
  unsigned short* ft = (unsigned short*)d_ws;  // kB*kHW*kC*2 = 15.6 MB scratch

  hipLaunchKernelGGL(transpose_k, dim3(kHW / 32, kC / 32, kB), dim3(8, 32), 0,
                     stream, feat, ft);
  hipLaunchKernelGGL(roialign_k, dim3(kN), dim3(kThreads), 0, stream, ft, rois, out);
}